// Round 5
// baseline (375.887 us; speedup 1.0000x reference)
//
#include <hip/hip_runtime.h>

// CBOW negative-sampling loss on MI355X.
#define BATCH 16384
#define CTX 10
#define EMB 256             // 64 float4 per row
#define TASKS (BATCH * 2)   // pos + neg side per batch element
#define T 4                 // tasks per wave
#define WAVES 4             // waves per block (256 threads)
#define BLOCKS (TASKS / (T * WAVES))  // 2048 = 8 blocks/CU resident

// Native clang vector type — __builtin_nontemporal_load requires a pointer
// to scalar/vector of scalars, not HIP_vector_type.
typedef float f4 __attribute__((ext_vector_type(4)));

// Non-temporal gather: rows have ~no L1 reuse (cross-task reuse lives in
// L2/L3 on other CUs) — avoid L1 allocation on the miss path.
static __device__ __forceinline__ f4 ntload(const f4* p) {
    return __builtin_nontemporal_load(p);
}

// One wave handles T tasks; lane i owns float4 slice [4i,4i+3] of the row.
// Per task: 11 gathered 1KB rows loaded into NAMED f4 temps (static
// indexing -> registers), tree-reduced, dotted, 64-lane butterfly,
// log-sigmoid. Index loads are cooperative (lanes 0..CTX) + shfl broadcast.
__global__ __launch_bounds__(256) void cbow_loss_kernel(
    const int* __restrict__ pos_u, const int* __restrict__ pos_w,
    const int* __restrict__ neg_u, const int* __restrict__ neg_w,
    const float* __restrict__ u_weight, const float* __restrict__ w_weight,
    float* __restrict__ out)
{
    __shared__ float wave_sum[WAVES];

    const int lane  = threadIdx.x & 63;
    const int wave  = threadIdx.x >> 6;
    const int task0 = (blockIdx.x * WAVES + wave) * T;

    const f4* __restrict__ U = (const f4*)u_weight;  // row stride 64
    const f4* __restrict__ W = (const f4*)w_weight;

    // Phase 0: cooperative index loads for all T tasks (latencies overlap).
    int iv[T];
#pragma unroll
    for (int t = 0; t < T; ++t) {
        const int task = task0 + t;
        const int b    = task >> 1;
        const int neg  = task & 1;
        const int* __restrict__ ui = neg ? neg_u : pos_u;
        const int* __restrict__ wi = neg ? neg_w : pos_w;
        int v = 0;
        if (lane <= CTX) v = (lane < CTX) ? ui[b * CTX + lane] : wi[b];
        iv[t] = v;
    }

    float lsum = 0.f;
#pragma unroll
    for (int t = 0; t < T; ++t) {
        const int neg = (task0 + t) & 1;

        // Broadcast the 11 row indices for this task.
        const int r0 = __shfl(iv[t], 0, 64);
        const int r1 = __shfl(iv[t], 1, 64);
        const int r2 = __shfl(iv[t], 2, 64);
        const int r3 = __shfl(iv[t], 3, 64);
        const int r4 = __shfl(iv[t], 4, 64);
        const int r5 = __shfl(iv[t], 5, 64);
        const int r6 = __shfl(iv[t], 6, 64);
        const int r7 = __shfl(iv[t], 7, 64);
        const int r8 = __shfl(iv[t], 8, 64);
        const int r9 = __shfl(iv[t], 9, 64);
        const int rw = __shfl(iv[t], CTX, 64);

        // Issue all 11 independent 1KB row gathers into named temps.
        const f4 v0 = ntload(&U[(size_t)r0 * 64 + lane]);
        const f4 v1 = ntload(&U[(size_t)r1 * 64 + lane]);
        const f4 v2 = ntload(&U[(size_t)r2 * 64 + lane]);
        const f4 v3 = ntload(&U[(size_t)r3 * 64 + lane]);
        const f4 v4 = ntload(&U[(size_t)r4 * 64 + lane]);
        const f4 v5 = ntload(&U[(size_t)r5 * 64 + lane]);
        const f4 v6 = ntload(&U[(size_t)r6 * 64 + lane]);
        const f4 v7 = ntload(&U[(size_t)r7 * 64 + lane]);
        const f4 v8 = ntload(&U[(size_t)r8 * 64 + lane]);
        const f4 v9 = ntload(&U[(size_t)r9 * 64 + lane]);
        const f4 wv = ntload(&W[(size_t)rw * 64 + lane]);

        // Tree reduce (short dep chain, consumes loads in issue order).
        const f4 s01 = v0 + v1;
        const f4 s23 = v2 + v3;
        const f4 s45 = v4 + v5;
        const f4 s67 = v6 + v7;
        const f4 s89 = v8 + v9;
        const f4 a0  = s01 + s23;
        const f4 a1  = s45 + s67;
        const f4 acc = a0 + a1 + s89;

        float p = acc.x * wv.x + acc.y * wv.y + acc.z * wv.z + acc.w * wv.w;
#pragma unroll
        for (int m = 32; m >= 1; m >>= 1)
            p += __shfl_xor(p, m, 64);

        const float x = neg ? -p : p;
        lsum += fminf(x, 0.f) - log1pf(expf(-fabsf(x)));  // log_sigmoid
    }

    if (lane == 0) wave_sum[wave] = -lsum;   // loss = -(sum of scores)
    __syncthreads();

    if (threadIdx.x == 0) {
        float s = 0.f;
#pragma unroll
        for (int w = 0; w < WAVES; ++w) s += wave_sum[w];
        atomicAdd(out, s);
    }
}

extern "C" void kernel_launch(void* const* d_in, const int* in_sizes, int n_in,
                              void* d_out, int out_size, void* d_ws, size_t ws_size,
                              hipStream_t stream) {
    const int*   pos_u    = (const int*)d_in[0];
    const int*   pos_w    = (const int*)d_in[1];
    const int*   neg_u    = (const int*)d_in[2];
    const int*   neg_w    = (const int*)d_in[3];
    const float* u_weight = (const float*)d_in[4];
    const float* w_weight = (const float*)d_in[5];
    float*       out      = (float*)d_out;

    // d_out is poisoned to 0xAA before every run; zero it (async, capture-safe).
    (void)hipMemsetAsync(out, 0, sizeof(float), stream);

    cbow_loss_kernel<<<BLOCKS, 256, 0, stream>>>(
        pos_u, pos_w, neg_u, neg_w, u_weight, w_weight, out);
}